// Round 1
// baseline (273.613 us; speedup 1.0000x reference)
//
#include <hip/hip_runtime.h>

#define D_DIM 2048
#define E_NUM 64
#define M_TOK 16384          // B*L = 4*4096
#define BM 64
#define BK 64
#define SPLITK 2
#define KSPLIT (D_DIM / SPLITK)   // 1024
#define XS_STRIDE 68         // 64 + 4 pad: keeps 16B alignment for b128, 8-way only on stores

// ws layout: partials [SPLITK][M_TOK][E_NUM] f32 (8 MB), then gprob[64], gcnt[64]

__global__ __launch_bounds__(128) void init_kernel(float* __restrict__ g) {
    g[threadIdx.x] = 0.0f;   // zeroes gprob[64] + gcnt[64]
}

__global__ __launch_bounds__(256, 2) void gemm_kernel(
    const float* __restrict__ x, const float* __restrict__ W,
    float* __restrict__ part)
{
    __shared__ float xs[BM * XS_STRIDE];   // [row][k] natural
    __shared__ float wl[BK * E_NUM];       // [k][e], e swizzled in 4-col blocks: cb' = cb ^ (k&15)

    const int tid  = threadIdx.x;
    const int tx   = tid & 15;             // expert quad index (4 experts)
    const int ty   = tid >> 4;             // token quad index (4 tokens)
    const int lrow = tid >> 4;             // staging row within 16-row pass
    const int lk4  = (tid & 15) << 2;      // staging k offset 0..60
    const long tokbase = (long)blockIdx.x * BM;
    const int  kbase   = blockIdx.y * KSPLIT;

    double accd[4][4];
    float  accc[4][4];
    #pragma unroll
    for (int i = 0; i < 4; ++i)
        #pragma unroll
        for (int j = 0; j < 4; ++j) { accd[i][j] = 0.0; accc[i][j] = 0.0f; }

    for (int it = 0; it < KSPLIT / BK; ++it) {
        const int k0 = kbase + it * BK;
        // ---- stage x: 64 rows x 64 k, coalesced float4 loads ----
        #pragma unroll
        for (int p = 0; p < 4; ++p) {
            const int row = p * 16 + lrow;
            const float4 xv = *(const float4*)&x[(tokbase + row) * D_DIM + k0 + lk4];
            *(float4*)&xs[row * XS_STRIDE + lk4] = xv;
        }
        // ---- stage W transposed + swizzled ----
        #pragma unroll
        for (int p = 0; p < 4; ++p) {
            const int e  = p * 16 + lrow;
            const float4 wv = *(const float4*)&W[(long)e * D_DIM + k0 + lk4];
            const int cb = e >> 2, ci = e & 3;
            wl[(lk4 + 0) * E_NUM + ((cb ^ ((lk4 + 0) & 15)) << 2) + ci] = wv.x;
            wl[(lk4 + 1) * E_NUM + ((cb ^ ((lk4 + 1) & 15)) << 2) + ci] = wv.y;
            wl[(lk4 + 2) * E_NUM + ((cb ^ ((lk4 + 2) & 15)) << 2) + ci] = wv.z;
            wl[(lk4 + 3) * E_NUM + ((cb ^ ((lk4 + 3) & 15)) << 2) + ci] = wv.w;
        }
        __syncthreads();
        // ---- compute: 4x4 frag per thread; fold fp32 chunk -> fp64 every 16 k ----
        #pragma unroll
        for (int kf = 0; kf < 4; ++kf) {
            #pragma unroll
            for (int kb = 0; kb < 4; ++kb) {
                const int kkb = kf * 16 + kb * 4;
                float xrf[16];
                #pragma unroll
                for (int i = 0; i < 4; ++i) {
                    const float4 v = *(const float4*)&xs[(ty * 4 + i) * XS_STRIDE + kkb];
                    xrf[i * 4 + 0] = v.x; xrf[i * 4 + 1] = v.y;
                    xrf[i * 4 + 2] = v.z; xrf[i * 4 + 3] = v.w;
                }
                #pragma unroll
                for (int k2 = 0; k2 < 4; ++k2) {
                    const int kk = kkb + k2;
                    const float4 wq = *(const float4*)&wl[kk * E_NUM + ((tx ^ (kk & 15)) << 2)];
                    const float wqf[4] = { wq.x, wq.y, wq.z, wq.w };
                    #pragma unroll
                    for (int i = 0; i < 4; ++i)
                        #pragma unroll
                        for (int j = 0; j < 4; ++j)
                            accc[i][j] += xrf[i * 4 + k2] * wqf[j];
                }
            }
            #pragma unroll
            for (int i = 0; i < 4; ++i)
                #pragma unroll
                for (int j = 0; j < 4; ++j) { accd[i][j] += (double)accc[i][j]; accc[i][j] = 0.0f; }
        }
        __syncthreads();
    }
    // ---- write fp32 partials, coalesced float4 ----
    float* dst = part + (size_t)blockIdx.y * ((size_t)M_TOK * E_NUM);
    #pragma unroll
    for (int i = 0; i < 4; ++i) {
        const long m = tokbase + ty * 4 + i;
        float4 v;
        v.x = (float)accd[i][0]; v.y = (float)accd[i][1];
        v.z = (float)accd[i][2]; v.w = (float)accd[i][3];
        *(float4*)&dst[m * E_NUM + (tx << 2)] = v;
    }
}

__global__ __launch_bounds__(256) void topk_kernel(
    const float* __restrict__ part, float* __restrict__ out,
    float* __restrict__ gprob, float* __restrict__ gcnt)
{
    __shared__ float pacc[4][E_NUM];
    __shared__ float cacc[4][E_NUM];
    const int w    = threadIdx.x >> 6;
    const int lane = threadIdx.x & 63;
    pacc[w][lane] = 0.0f;
    cacc[w][lane] = 0.0f;
    const int gw = blockIdx.x * 4 + w;        // 1024 waves, 16 tokens each

    for (int i = 0; i < 16; ++i) {
        const int t = gw * 16 + i;
        const float l = part[(size_t)t * E_NUM + lane]
                      + part[((size_t)M_TOK + t) * E_NUM + lane];
        // top-1 (max, lowest index on tie — matches jax.lax.top_k)
        float m1 = l; int i1 = lane;
        #pragma unroll
        for (int off = 32; off > 0; off >>= 1) {
            const float ov = __shfl_xor(m1, off, 64);
            const int   oi = __shfl_xor(i1, off, 64);
            if (ov > m1 || (ov == m1 && oi < i1)) { m1 = ov; i1 = oi; }
        }
        // full softmax prob for aux loss
        const float p = __expf(l - m1);
        float s = p;
        #pragma unroll
        for (int off = 32; off > 0; off >>= 1) s += __shfl_xor(s, off, 64);
        pacc[w][lane] += p / s;
        if (lane == i1) cacc[w][lane] += 1.0f;
        // top-2
        const float lm = (lane == i1) ? -1e30f : l;
        float m2 = lm; int i2 = lane;
        #pragma unroll
        for (int off = 32; off > 0; off >>= 1) {
            const float ov = __shfl_xor(m2, off, 64);
            const int   oi = __shfl_xor(i2, off, 64);
            if (ov > m2 || (ov == m2 && oi < i2)) { m2 = ov; i2 = oi; }
        }
        if (lane == 0) {
            out[2 * t]     = (float)i1;
            out[2 * t + 1] = (float)i2;
            const float w1 = 1.0f / (1.0f + __expf(m2 - m1));
            out[2 * M_TOK + 2 * t]     = w1;
            out[2 * M_TOK + 2 * t + 1] = 1.0f - w1;
        }
    }
    __syncthreads();
    if (threadIdx.x < E_NUM) {
        const int e = threadIdx.x;
        atomicAdd(&gprob[e], pacc[0][e] + pacc[1][e] + pacc[2][e] + pacc[3][e]);
        atomicAdd(&gcnt[e],  cacc[0][e] + cacc[1][e] + cacc[2][e] + cacc[3][e]);
    }
}

__global__ __launch_bounds__(64) void aux_kernel(
    const float* __restrict__ gprob, const float* __restrict__ gcnt,
    float* __restrict__ out)
{
    const int lane = threadIdx.x;
    float v = gprob[lane] * gcnt[lane];
    #pragma unroll
    for (int off = 32; off > 0; off >>= 1) v += __shfl_xor(v, off, 64);
    if (lane == 0)
        out[4 * M_TOK] = 64.0f * 0.01f * v / ((float)M_TOK * (float)M_TOK);
}

extern "C" void kernel_launch(void* const* d_in, const int* in_sizes, int n_in,
                              void* d_out, int out_size, void* d_ws, size_t ws_size,
                              hipStream_t stream)
{
    const float* x = (const float*)d_in[0];
    const float* W = (const float*)d_in[1];
    float* out   = (float*)d_out;
    float* part  = (float*)d_ws;                                   // 8 MB
    float* gprob = part + (size_t)SPLITK * M_TOK * E_NUM;
    float* gcnt  = gprob + E_NUM;

    init_kernel<<<1, 128, 0, stream>>>(gprob);
    gemm_kernel<<<dim3(M_TOK / BM, SPLITK), 256, 0, stream>>>(x, W, part);
    topk_kernel<<<M_TOK / 64, 256, 0, stream>>>(part, out, gprob, gcnt);
    aux_kernel<<<1, 64, 0, stream>>>(gprob, gcnt, out);
}